// Round 1
// baseline (1839.484 us; speedup 1.0000x reference)
//
#include <hip/hip_runtime.h>

#define Bsz   1024
#define Tlen  512
#define VOC   8
#define EDIM  32
#define HDIM  64
#define G4    256   // 4*H gate rows

// broadcast lane j of a wave-uniform-content VGPR to all lanes via SGPR
__device__ __forceinline__ float rl(float v, int lane) {
    return __uint_as_float(__builtin_amdgcn_readlane(__float_as_uint(v), lane));
}

__device__ __forceinline__ float sigm(float x) {
    return 1.0f / (1.0f + __expf(-x));
}
__device__ __forceinline__ float tanh_(float x) {
    float e2 = __expf(-2.0f * fabsf(x));          // in (0,1]
    float t  = (1.0f - e2) / (1.0f + e2);
    return copysignf(t, x);
}

// ws layout: [0 .. 8*256) = G0 table (gates from embedding, layer0, incl. both biases)
//            [8*256 .. 8*256+256) = bih1+bhh1
__global__ void precompute_kernel(const float* __restrict__ emb,
                                  const float* __restrict__ Wih0,
                                  const float* __restrict__ bih0,
                                  const float* __restrict__ bhh0,
                                  const float* __restrict__ bih1,
                                  const float* __restrict__ bhh1,
                                  float* __restrict__ ws) {
    int g = threadIdx.x;
    int v = blockIdx.x;
    if (v < VOC) {
        float acc = bih0[g] + bhh0[g];
        #pragma unroll
        for (int e = 0; e < EDIM; ++e)
            acc += Wih0[g * EDIM + e] * emb[v * EDIM + e];
        ws[v * G4 + g] = acc;
    } else {
        ws[VOC * G4 + g] = bih1[g] + bhh1[g];
    }
}

__global__ __launch_bounds__(256, 2)
void lstm_kernel(const int*   __restrict__ x,
                 const float* __restrict__ Whh0,
                 const float* __restrict__ Wih1,
                 const float* __restrict__ Whh1,
                 const float* __restrict__ Wfc,
                 const float* __restrict__ bfc,
                 const float* __restrict__ ws,
                 float* __restrict__ out) {
    __shared__ float sG0[VOC * G4];   // 8 KB gate table
    __shared__ int   sx[Tlen];        // 2 KB this sequence's tokens
    __shared__ float sh0[HDIM], sh1[HDIM];
    __shared__ float sact0[G4], sact1[G4];

    const int tid  = threadIdx.x;
    const int b    = blockIdx.x;
    const int lane = tid & 63;
    const int arow = tid >> 6;        // wave id == gate type: 0=i 1=f 2=g 3=o

    // stage the token-gate table and token stream
    #pragma unroll
    for (int i = 0; i < (VOC * G4) / 256; ++i)
        sG0[i * 256 + tid] = ws[i * 256 + tid];
    #pragma unroll
    for (int i = 0; i < Tlen / 256; ++i)
        sx[i * 256 + tid] = x[b * Tlen + i * 256 + tid];
    if (tid < HDIM) { sh0[tid] = 0.0f; sh1[tid] = 0.0f; }
    const float b1 = ws[VOC * G4 + tid];

    // thread g owns gate-row g of all three recurrent matrices, in registers
    float w0[HDIM], wi1[HDIM], wh1[HDIM];
    {
        const float4* p0 = (const float4*)(Whh0 + tid * HDIM);
        const float4* p1 = (const float4*)(Wih1 + tid * HDIM);
        const float4* p2 = (const float4*)(Whh1 + tid * HDIM);
        #pragma unroll
        for (int i = 0; i < HDIM / 4; ++i) {
            float4 a = p0[i];
            w0[4*i+0]=a.x; w0[4*i+1]=a.y; w0[4*i+2]=a.z; w0[4*i+3]=a.w;
            float4 bq = p1[i];
            wi1[4*i+0]=bq.x; wi1[4*i+1]=bq.y; wi1[4*i+2]=bq.z; wi1[4*i+3]=bq.w;
            float4 c = p2[i];
            wh1[4*i+0]=c.x; wh1[4*i+1]=c.y; wh1[4*i+2]=c.z; wh1[4*i+3]=c.w;
        }
    }

    float c0 = 0.0f, c1 = 0.0f;     // cell state: lane j of wave0 holds c0[j]; wave1 holds c1[j]
    float vh0 = 0.0f, vh1 = 0.0f;   // lane j holds h0[j], h1[j] (for readlane broadcast)
    __syncthreads();

    // layer1 pipelined one step behind layer0: iter k does layer0@t=k and layer1@t=k-1
    #pragma unroll 1
    for (int k = 0; k <= Tlen; ++k) {
        const int xk = sx[k < Tlen ? k : (Tlen - 1)];
        float a0a = sG0[xk * G4 + tid], a0b = 0.0f;
        float a1a = b1, a1b = 0.0f, a1c = 0.0f, a1d = 0.0f;
        #pragma unroll
        for (int j = 0; j < HDIM; j += 2) {
            float h0j  = rl(vh0, j);
            float h0j1 = rl(vh0, j + 1);
            float h1j  = rl(vh1, j);
            float h1j1 = rl(vh1, j + 1);
            a0a += w0[j]    * h0j;
            a0b += w0[j+1]  * h0j1;
            a1a += wi1[j]   * h0j;
            a1b += wi1[j+1] * h0j1;
            a1c += wh1[j]   * h1j;
            a1d += wh1[j+1] * h1j1;
        }
        float a0 = a0a + a0b;
        float a1 = (a1a + a1b) + (a1c + a1d);
        // wave-uniform activation select (one wave per gate type)
        sact0[tid] = (arow == 2) ? tanh_(a0) : sigm(a0);
        sact1[tid] = (arow == 2) ? tanh_(a1) : sigm(a1);
        __syncthreads();

        if (tid < HDIM) {                     // wave 0: update layer0 state
            if (k < Tlen) {
                float gi = sact0[tid], gf = sact0[HDIM + tid];
                float gg = sact0[2*HDIM + tid], go = sact0[3*HDIM + tid];
                c0 = gf * c0 + gi * gg;
                sh0[tid] = go * tanh_(c0);
            }
        } else if (tid < 2 * HDIM) {          // wave 1: update layer1 state
            if (k >= 1) {
                int j = tid - HDIM;
                float gi = sact1[j], gf = sact1[HDIM + j];
                float gg = sact1[2*HDIM + j], go = sact1[3*HDIM + j];
                c1 = gf * c1 + gi * gg;
                sh1[j] = go * tanh_(c1);
            }
        }
        __syncthreads();
        vh0 = sh0[lane];
        vh1 = sh1[lane];
    }

    // logits = h1(T-1) @ Wfc^T + bfc
    if (tid < VOC) {
        float acc = bfc[tid];
        #pragma unroll
        for (int j = 0; j < HDIM; ++j)
            acc += Wfc[tid * HDIM + j] * sh1[j];
        out[b * VOC + tid] = acc;
    }
}

extern "C" void kernel_launch(void* const* d_in, const int* in_sizes, int n_in,
                              void* d_out, int out_size, void* d_ws, size_t ws_size,
                              hipStream_t stream) {
    const int*   x    = (const int*)  d_in[0];
    const float* emb  = (const float*)d_in[1];
    const float* Wih0 = (const float*)d_in[2];
    const float* Whh0 = (const float*)d_in[3];
    const float* bih0 = (const float*)d_in[4];
    const float* bhh0 = (const float*)d_in[5];
    const float* Wih1 = (const float*)d_in[6];
    const float* Whh1 = (const float*)d_in[7];
    const float* bih1 = (const float*)d_in[8];
    const float* bhh1 = (const float*)d_in[9];
    const float* Wfc  = (const float*)d_in[10];
    const float* bfc  = (const float*)d_in[11];
    float* out = (float*)d_out;
    float* ws  = (float*)d_ws;

    hipLaunchKernelGGL(precompute_kernel, dim3(VOC + 1), dim3(G4), 0, stream,
                       emb, Wih0, bih0, bhh0, bih1, bhh1, ws);
    hipLaunchKernelGGL(lstm_kernel, dim3(Bsz), dim3(G4), 0, stream,
                       x, Whh0, Wih1, Whh1, Wfc, bfc, ws, out);
}